// Round 2
// baseline (10601.757 us; speedup 1.0000x reference)
//
#include <hip/hip_runtime.h>

// ---------------- problem constants ----------------
#define BB 256   // batch
#define TT 256   // time steps
#define II 16    // input dim (layer 0)
#define HH 512   // hidden
#define G4 2048  // 4*H
#define LL 4     // layers

typedef float f32x4 __attribute__((ext_vector_type(4)));
typedef _Float16 f16x8 __attribute__((ext_vector_type(8)));
typedef _Float16 f16x4 __attribute__((ext_vector_type(4)));
typedef float f32x4v __attribute__((ext_vector_type(4)));
typedef unsigned int u32x4 __attribute__((ext_vector_type(4)));

#define MFMA16(a, b, c) __builtin_amdgcn_mfma_f32_16x16x32_f16((a), (b), (c), 0, 0, 0)

// ---------------- static device state ----------------
__device__ _Float16 g_hbuf[(size_t)LL * BB * TT * HH];   // h sequence per layer
__device__ _Float16 g_xbf[(size_t)BB * TT * II];         // x in f16
__device__ _Float16 g_wih0[G4 * II];                     // layer0 w_ih
__device__ _Float16 g_whh[(size_t)LL * G4 * HH];         // w_hh all layers
__device__ _Float16 g_wihr[(size_t)3 * G4 * HH];         // w_ih layers 1..3
__device__ float    g_bias[LL * G4];                     // b_ih + b_hh per layer
__device__ unsigned g_cnt[32 * 64];                      // per-(layer,group) counters, padded

// ---------------- helpers ----------------
__device__ __forceinline__ void st_cv(void* p, unsigned v) {
  asm volatile("global_store_dword %0, %1, off sc0 sc1" : : "v"(p), "v"(v) : "memory");
}
__device__ __forceinline__ float fsig(float x) { return 1.f / (1.f + __expf(-x)); }
__device__ __forceinline__ float ftanh(float x) { return 1.f - 2.f / (__expf(2.f * x) + 1.f); }

__device__ __forceinline__ unsigned ld_ctr(const unsigned* p) {
  return __hip_atomic_load(p, __ATOMIC_RELAXED, __HIP_MEMORY_SCOPE_AGENT);
}

// A-fragment read from swizzled LDS tile [32][512] f16
__device__ __forceinline__ f16x8 ldsA(const _Float16* base, int mt, int kt, int lane) {
  int row = mt * 16 + (lane & 15);
  int off = (row << 10) + (kt << 6) + ((lane >> 4) << 4);
  off ^= (lane & 15) << 4;
  return *(const f16x8*)((const char*)base + off);
}

// ---------------- prep: fp32 -> fp16 conversions, bias sums, counter reset ----------------
__device__ __forceinline__ void cv4(_Float16* d, const float* s, size_t n4, size_t tid, size_t stride) {
  for (size_t i = tid; i < n4; i += stride) {
    f32x4v v = ((const f32x4v*)s)[i];
    ((f16x4*)d)[i] = __builtin_convertvector(v, f16x4);
  }
}

__global__ void prep_kernel(const float* __restrict__ x, const float* __restrict__ wih0,
                            const float* __restrict__ whh0, const float* __restrict__ bih0,
                            const float* __restrict__ bhh0, const float* __restrict__ wihr,
                            const float* __restrict__ whhr, const float* __restrict__ bihr,
                            const float* __restrict__ bhhr) {
  size_t tid = (size_t)blockIdx.x * blockDim.x + threadIdx.x;
  size_t stride = (size_t)gridDim.x * blockDim.x;
  cv4(g_xbf, x, (size_t)BB * TT * II / 4, tid, stride);
  cv4(g_wih0, wih0, (size_t)G4 * II / 4, tid, stride);
  cv4(g_whh, whh0, (size_t)G4 * HH / 4, tid, stride);
  cv4(g_whh + (size_t)G4 * HH, whhr, (size_t)3 * G4 * HH / 4, tid, stride);
  cv4(g_wihr, wihr, (size_t)3 * G4 * HH / 4, tid, stride);
  for (size_t i = tid; i < G4; i += stride) g_bias[i] = bih0[i] + bhh0[i];
  for (size_t i = tid; i < 3 * G4; i += stride) g_bias[G4 + i] = bihr[i] + bhhr[i];
  if (tid < 32) g_cnt[tid * 64] = 0u;
}

// ---------------- persistent LSTM kernel, depth-2 layer pipeline ----------------
// grid = 512 blocks x 256 threads (2 blocks/CU guaranteed by launch_bounds).
// stage s = bid>>8 (0/1); within stage: group g = bid&7 owns batch rows [32g,32g+32);
// block jc = (bid>>3)&31 owns h-cols [16jc,16jc+16). Pass p: stage s runs layer 2p+s.
// Layer l's 32 blocks (per group) bump g_cnt[(l*8+g)*64] once per completed step.
// Consumers poll: x-dep  -> cnt[l-1][g] >= 32(t+1); own-h -> cnt[l][g] >= 32 t.
__global__ __launch_bounds__(256, 2) void lstm_kernel() {
  const int tid = threadIdx.x;
  const int s = blockIdx.x >> 8;
  const int g = blockIdx.x & 7;
  const int jc = (blockIdx.x >> 3) & 31;
  const int w = tid >> 6;
  const int lane = tid & 63;
  const int col = lane & 15, kg = lane >> 4;
  const int n0 = w * 512 + jc * 16;

  __shared__ _Float16 xs[32 * 512];
  __shared__ _Float16 hs[32 * 512];
  __shared__ float gbuf[4][32 * 17];

  const int eb = tid >> 3;        // elementwise: batch row 0..31
  const int ej = (tid & 7) * 2;   // elementwise: h-col pair within block's 16

  f16x8 wihf[16], whhf[16];

  for (int pass = 0; pass < 2; ++pass) {
    const int l = 2 * pass + s;

    // ---- per-layer: load weight fragments into registers ----
    {
      const _Float16* wb = g_whh + ((size_t)l * G4 + (n0 + col)) * HH + kg * 8;
#pragma unroll
      for (int kt = 0; kt < 16; ++kt) whhf[kt] = *(const f16x8*)(wb + kt * 32);
      if (l == 0) {
        if (kg < 2) wihf[0] = *(const f16x8*)(g_wih0 + (n0 + col) * II + kg * 8);
        else { f16x8 z = {}; wihf[0] = z; }
      } else {
        const _Float16* wi = g_wihr + ((size_t)(l - 1) * G4 + (n0 + col)) * HH + kg * 8;
#pragma unroll
        for (int kt = 0; kt < 16; ++kt) wihf[kt] = *(const f16x8*)(wi + kt * 32);
      }
    }
    const float bias = g_bias[l * G4 + n0 + col];
    float c0 = 0.f, c1 = 0.f;

    const _Float16* xsrc = g_hbuf + ((size_t)(l - 1) * BB + 32 * g) * TT * HH;  // valid for l>0
    _Float16* hdst = g_hbuf + ((size_t)l * BB + 32 * g) * TT * HH;
    const unsigned* cprod = &g_cnt[((l - 1) * 8 + g) * 64];
    unsigned* cown = &g_cnt[(l * 8 + g) * 64];

    for (int t = 0; t < TT; ++t) {
      // ---- wait for dependencies (producer x-tile; own h-tile) ----
      if (tid == 0) {
        if (l > 0) {
          unsigned tgt = 32u * (unsigned)(t + 1);
          while (ld_ctr(cprod) < tgt) __builtin_amdgcn_s_sleep(1);
        }
        if (t > 0) {
          unsigned tgt = 32u * (unsigned)t;
          while (ld_ctr(cown) < tgt) __builtin_amdgcn_s_sleep(1);
        }
      }
      __syncthreads();

      // ---- issue all global loads (plain cached; write-through stores + once-written
      //      addresses + post-barrier reads make these coherence-safe) ----
      u32x4 vx[8], vh[8], vx0;
      if (l > 0) {
        const _Float16* sx = xsrc + (size_t)t * HH;
#pragma unroll
        for (int it = 0; it < 8; ++it) {
          int q = tid + it * 256, row = q >> 6, c16 = q & 63;
          vx[it] = *(const u32x4*)((const char*)(sx + (size_t)row * TT * HH) + c16 * 16);
        }
      } else if (tid < 64) {
        int row = tid >> 1, half = tid & 1;
        vx0 = *(const u32x4*)(g_xbf + ((size_t)(32 * g + row) * TT + t) * II + half * 8);
      }
      if (t > 0) {
        const _Float16* sh = hdst + (size_t)(t - 1) * HH;
#pragma unroll
        for (int it = 0; it < 8; ++it) {
          int q = tid + it * 256, row = q >> 6, c16 = q & 63;
          vh[it] = *(const u32x4*)((const char*)(sh + (size_t)row * TT * HH) + c16 * 16);
        }
      }

      // ---- stage xs (swizzled), then x-GEMM while h loads are in flight ----
      if (l > 0) {
#pragma unroll
        for (int it = 0; it < 8; ++it) {
          int q = tid + it * 256, row = q >> 6, c16 = q & 63;
          int off = (row << 10) + (c16 << 4); off ^= (row & 15) << 4;
          *(u32x4*)((char*)xs + off) = vx[it];
        }
      } else {
        if (tid < 64) {
          int row = tid >> 1, half = tid & 1;
          int off = (row << 10) + (half << 4); off ^= (row & 15) << 4;
          *(u32x4*)((char*)xs + off) = vx0;
        } else if (tid < 128) {
          int q = tid - 64, row = q >> 1, half = q & 1;
          int off = (row << 10) + 32 + (half << 4); off ^= (row & 15) << 4;
          u32x4 z = {0u, 0u, 0u, 0u};
          *(u32x4*)((char*)xs + off) = z;
        }
      }
      __syncthreads();

      f32x4 acc0 = {bias, bias, bias, bias}, acc1 = acc0;
      if (l == 0) {
        acc0 = MFMA16(ldsA(xs, 0, 0, lane), wihf[0], acc0);
        acc1 = MFMA16(ldsA(xs, 1, 0, lane), wihf[0], acc1);
      } else {
#pragma unroll
        for (int kt = 0; kt < 16; ++kt) {
          acc0 = MFMA16(ldsA(xs, 0, kt, lane), wihf[kt], acc0);
          acc1 = MFMA16(ldsA(xs, 1, kt, lane), wihf[kt], acc1);
        }
      }

      // ---- stage hs, then h-GEMM ----
      if (t > 0) {
#pragma unroll
        for (int it = 0; it < 8; ++it) {
          int q = tid + it * 256, row = q >> 6, c16 = q & 63;
          int off = (row << 10) + (c16 << 4); off ^= (row & 15) << 4;
          *(u32x4*)((char*)hs + off) = vh[it];
        }
        __syncthreads();
#pragma unroll
        for (int kt = 0; kt < 16; ++kt) {
          acc0 = MFMA16(ldsA(hs, 0, kt, lane), whhf[kt], acc0);
          acc1 = MFMA16(ldsA(hs, 1, kt, lane), whhf[kt], acc1);
        }
      }

      // ---- publish gate tiles ----
#pragma unroll
      for (int r = 0; r < 4; ++r) {
        gbuf[w][(kg * 4 + r) * 17 + col] = acc0[r];
        gbuf[w][(16 + kg * 4 + r) * 17 + col] = acc1[r];
      }
      __syncthreads();

      // ---- elementwise LSTM cell (c kept in fp32 regs), store h slice ----
      {
        int i0 = eb * 17 + ej;
        float i_0 = fsig(gbuf[0][i0]),  i_1 = fsig(gbuf[0][i0 + 1]);
        float f_0 = fsig(gbuf[1][i0]),  f_1 = fsig(gbuf[1][i0 + 1]);
        float t_0 = ftanh(gbuf[2][i0]), t_1 = ftanh(gbuf[2][i0 + 1]);
        float o_0 = fsig(gbuf[3][i0]),  o_1 = fsig(gbuf[3][i0 + 1]);
        c0 = f_0 * c0 + i_0 * t_0;
        c1 = f_1 * c1 + i_1 * t_1;
        float h0 = o_0 * ftanh(c0), h1 = o_1 * ftanh(c1);
        _Float16 hh0 = (_Float16)h0, hh1 = (_Float16)h1;
        unsigned pv = ((unsigned)__builtin_bit_cast(unsigned short, hh1) << 16) |
                      (unsigned)__builtin_bit_cast(unsigned short, hh0);
        _Float16* dst = hdst + ((size_t)eb * TT + t) * HH + jc * 16 + ej;
        st_cv(dst, pv);
      }

      // ---- drain stores, then signal step completion (no wait here) ----
      asm volatile("s_waitcnt vmcnt(0)" ::: "memory");
      __syncthreads();
      if (tid == 0) {
        __hip_atomic_fetch_add(cown, 1u, __ATOMIC_RELAXED, __HIP_MEMORY_SCOPE_AGENT);
      }
    }
  }
}

// ---------------- FC head: out[b] = sigmoid(h_last[b] . fc_w + fc_b) ----------------
__global__ void fc_kernel(const float* __restrict__ fcw, const float* __restrict__ fcb,
                          float* __restrict__ out) {
  int b = blockIdx.x, lane = threadIdx.x;
  const _Float16* h = g_hbuf + ((size_t)3 * BB + b) * TT * HH + (size_t)(TT - 1) * HH + lane * 8;
  f16x8 hv = *(const f16x8*)h;
  const float* wp = fcw + lane * 8;
  float s = 0.f;
#pragma unroll
  for (int j = 0; j < 8; ++j) s += (float)hv[j] * wp[j];
#pragma unroll
  for (int off = 32; off; off >>= 1) s += __shfl_down(s, off, 64);
  if (lane == 0) out[b] = 1.f / (1.f + __expf(-(s + fcb[0])));
}

// ---------------- launch ----------------
extern "C" void kernel_launch(void* const* d_in, const int* in_sizes, int n_in,
                              void* d_out, int out_size, void* d_ws, size_t ws_size,
                              hipStream_t stream) {
  const float* x    = (const float*)d_in[0];
  const float* wih0 = (const float*)d_in[1];
  const float* whh0 = (const float*)d_in[2];
  const float* bih0 = (const float*)d_in[3];
  const float* bhh0 = (const float*)d_in[4];
  const float* wihr = (const float*)d_in[5];
  const float* whhr = (const float*)d_in[6];
  const float* bihr = (const float*)d_in[7];
  const float* bhhr = (const float*)d_in[8];
  const float* fcw  = (const float*)d_in[9];
  const float* fcb  = (const float*)d_in[10];

  prep_kernel<<<dim3(1024), dim3(256), 0, stream>>>(x, wih0, whh0, bih0, bhh0,
                                                    wihr, whhr, bihr, bhhr);
  lstm_kernel<<<dim3(512), dim3(256), 0, stream>>>();
  fc_kernel<<<dim3(256), dim3(64), 0, stream>>>(fcw, fcb, (float*)d_out);
}

// Round 3
// 4993.763 us; speedup vs baseline: 2.1230x; 2.1230x over previous
//
#include <hip/hip_runtime.h>

// ---------------- problem constants ----------------
#define BB 256   // batch
#define TT 256   // time steps
#define II 16    // input dim (layer 0)
#define HH 512   // hidden
#define G4 2048  // 4*H
#define LL 4     // layers

typedef float f32x4 __attribute__((ext_vector_type(4)));
typedef _Float16 f16x8 __attribute__((ext_vector_type(8)));
typedef _Float16 f16x4 __attribute__((ext_vector_type(4)));
typedef float f32x4v __attribute__((ext_vector_type(4)));
typedef unsigned int u32x4 __attribute__((ext_vector_type(4)));

#define MFMA16(a, b, c) __builtin_amdgcn_mfma_f32_16x16x32_f16((a), (b), (c), 0, 0, 0)

// ---------------- static device state ----------------
__device__ _Float16 g_hbuf[(size_t)LL * BB * TT * HH];   // h sequence per layer
__device__ _Float16 g_xbf[(size_t)BB * TT * II];         // x in f16
__device__ _Float16 g_wih0[G4 * II];                     // layer0 w_ih
__device__ _Float16 g_whh[(size_t)LL * G4 * HH];         // w_hh all layers
__device__ _Float16 g_wihr[(size_t)3 * G4 * HH];         // w_ih layers 1..3
__device__ float    g_bias[LL * G4];                     // b_ih + b_hh per layer
__device__ unsigned g_cnt[32 * 64];                      // per-group counters, padded

// ---------------- helpers ----------------
__device__ __forceinline__ void st_cv(void* p, unsigned v) {
  asm volatile("global_store_dword %0, %1, off sc0 sc1" : : "v"(p), "v"(v) : "memory");
}
__device__ __forceinline__ float fsig(float x) { return 1.f / (1.f + __expf(-x)); }
__device__ __forceinline__ float ftanh(float x) { return 1.f - 2.f / (__expf(2.f * x) + 1.f); }

__device__ __forceinline__ unsigned ld_ctr(const unsigned* p) {
  return __hip_atomic_load(p, __ATOMIC_RELAXED, __HIP_MEMORY_SCOPE_AGENT);
}

// A-fragment read from swizzled LDS tile [32][512] f16
__device__ __forceinline__ f16x8 ldsA(const _Float16* base, int mt, int kt, int lane) {
  int row = mt * 16 + (lane & 15);
  int off = (row << 10) + (kt << 6) + ((lane >> 4) << 4);
  off ^= (lane & 15) << 4;
  return *(const f16x8*)((const char*)base + off);
}

// ---------------- prep: fp32 -> fp16 conversions, bias sums, counter reset ----------------
__device__ __forceinline__ void cv4(_Float16* d, const float* s, size_t n4, size_t tid, size_t stride) {
  for (size_t i = tid; i < n4; i += stride) {
    f32x4v v = ((const f32x4v*)s)[i];
    ((f16x4*)d)[i] = __builtin_convertvector(v, f16x4);
  }
}

__global__ void prep_kernel(const float* __restrict__ x, const float* __restrict__ wih0,
                            const float* __restrict__ whh0, const float* __restrict__ bih0,
                            const float* __restrict__ bhh0, const float* __restrict__ wihr,
                            const float* __restrict__ whhr, const float* __restrict__ bihr,
                            const float* __restrict__ bhhr) {
  size_t tid = (size_t)blockIdx.x * blockDim.x + threadIdx.x;
  size_t stride = (size_t)gridDim.x * blockDim.x;
  cv4(g_xbf, x, (size_t)BB * TT * II / 4, tid, stride);
  cv4(g_wih0, wih0, (size_t)G4 * II / 4, tid, stride);
  cv4(g_whh, whh0, (size_t)G4 * HH / 4, tid, stride);
  cv4(g_whh + (size_t)G4 * HH, whhr, (size_t)3 * G4 * HH / 4, tid, stride);
  cv4(g_wihr, wihr, (size_t)3 * G4 * HH / 4, tid, stride);
  for (size_t i = tid; i < G4; i += stride) g_bias[i] = bih0[i] + bhh0[i];
  for (size_t i = tid; i < 3 * G4; i += stride) g_bias[G4 + i] = bihr[i] + bhhr[i];
  if (tid < 32) g_cnt[tid * 64] = 0u;
}

// ---------------- persistent LSTM kernel (single stage, all layers sequential) ----------------
// grid = 256 blocks x 256 threads, 1 block/CU (74KB LDS). group g = bid&7 (one XCD)
// owns batch rows [32g,32g+32); block jc = bid>>3 owns h-cols [16jc,16jc+16).
// Per step: stage x -> poll group counter -> issue h loads -> x-GEMM (covers h flight)
// -> stage hs -> h-GEMM (x_{t+1} prefetch under it) -> elementwise -> store+signal.
__global__ __launch_bounds__(256, 1) void lstm_kernel() {
  const int tid = threadIdx.x;
  const int g = blockIdx.x & 7;
  const int jc = blockIdx.x >> 3;
  const int w = tid >> 6;
  const int lane = tid & 63;
  const int col = lane & 15, kg = lane >> 4;
  const int n0 = w * 512 + jc * 16;

  __shared__ _Float16 xs[32 * 512];
  __shared__ _Float16 hs[32 * 512];
  __shared__ float gbuf[4][32 * 17];

  const int eb = tid >> 3;        // elementwise: batch row 0..31
  const int ej = (tid & 7) * 2;   // elementwise: h-col pair within block's 16

  f16x8 wihf[16], whhf[16];
  unsigned* cown = &g_cnt[g * 64];

  // one-time zero-pad of xs byte-cols [32,64) (used only by layer 0's K=16..31)
  if (tid < 64) {
    int row = tid >> 1, half = tid & 1;
    int off = (row << 10) + 32 + (half << 4); off ^= (row & 15) << 4;
    u32x4 z = {0u, 0u, 0u, 0u};
    *(u32x4*)((char*)xs + off) = z;
  }

  for (int l = 0; l < LL; ++l) {
    // ---- per-layer: load weight fragments into registers ----
    {
      const _Float16* wb = g_whh + ((size_t)l * G4 + (n0 + col)) * HH + kg * 8;
#pragma unroll
      for (int kt = 0; kt < 16; ++kt) whhf[kt] = *(const f16x8*)(wb + kt * 32);
      if (l == 0) {
        if (kg < 2) wihf[0] = *(const f16x8*)(g_wih0 + (n0 + col) * II + kg * 8);
        else { f16x8 z = {}; wihf[0] = z; }
      } else {
        const _Float16* wi = g_wihr + ((size_t)(l - 1) * G4 + (n0 + col)) * HH + kg * 8;
#pragma unroll
        for (int kt = 0; kt < 16; ++kt) wihf[kt] = *(const f16x8*)(wi + kt * 32);
      }
    }
    const float bias = g_bias[l * G4 + n0 + col];
    float c0 = 0.f, c1 = 0.f;

    const _Float16* xsrc = g_hbuf + ((size_t)(l - 1) * BB + 32 * g) * TT * HH;  // valid for l>0
    _Float16* hdst = g_hbuf + ((size_t)l * BB + 32 * g) * TT * HH;

    // ---- prologue: load x_0 into registers ----
    u32x4 vx[8], vx0;
    if (l > 0) {
#pragma unroll
      for (int it = 0; it < 8; ++it) {
        int q = tid + it * 256, row = q >> 6, c16 = q & 63;
        vx[it] = *(const u32x4*)((const char*)(xsrc + (size_t)row * TT * HH) + c16 * 16);
      }
    } else if (tid < 64) {
      int row = tid >> 1, half = tid & 1;
      vx0 = *(const u32x4*)(g_xbf + ((size_t)(32 * g + row) * TT) * II + half * 8);
    }

    for (int t = 0; t < TT; ++t) {
      // ---- stage x_t into LDS (swizzled) ----
      if (l > 0) {
#pragma unroll
        for (int it = 0; it < 8; ++it) {
          int q = tid + it * 256, row = q >> 6, c16 = q & 63;
          int off = (row << 10) + (c16 << 4); off ^= (row & 15) << 4;
          *(u32x4*)((char*)xs + off) = vx[it];
        }
      } else if (tid < 64) {
        int row = tid >> 1, half = tid & 1;
        int off = (row << 10) + (half << 4); off ^= (row & 15) << 4;
        *(u32x4*)((char*)xs + off) = vx0;
      }

      // ---- wait for h_{t-1} (tight spin; agent-scope relaxed load) ----
      if (t > 0 && tid == 0) {
        unsigned tgt = 32u * (unsigned)(l * TT + t);
        while (ld_ctr(cown) < tgt) {}
      }
      __syncthreads();

      // ---- issue h_{t-1} loads (plain cached: first toucher fills XCD L2) ----
      u32x4 vh[8];
      if (t > 0) {
        const _Float16* sh = hdst + (size_t)(t - 1) * HH;
#pragma unroll
        for (int it = 0; it < 8; ++it) {
          int q = tid + it * 256, row = q >> 6, c16 = q & 63;
          vh[it] = *(const u32x4*)((const char*)(sh + (size_t)row * TT * HH) + c16 * 16);
        }
      }

      // ---- x-GEMM while h loads are in flight ----
      f32x4 acc0 = {bias, bias, bias, bias}, acc1 = acc0;
      if (l == 0) {
        acc0 = MFMA16(ldsA(xs, 0, 0, lane), wihf[0], acc0);
        acc1 = MFMA16(ldsA(xs, 1, 0, lane), wihf[0], acc1);
      } else {
#pragma unroll
        for (int kt = 0; kt < 16; ++kt) {
          acc0 = MFMA16(ldsA(xs, 0, kt, lane), wihf[kt], acc0);
          acc1 = MFMA16(ldsA(xs, 1, kt, lane), wihf[kt], acc1);
        }
      }

      // ---- stage hs, prefetch x_{t+1}, h-GEMM ----
      if (t > 0) {
#pragma unroll
        for (int it = 0; it < 8; ++it) {
          int q = tid + it * 256, row = q >> 6, c16 = q & 63;
          int off = (row << 10) + (c16 << 4); off ^= (row & 15) << 4;
          *(u32x4*)((char*)hs + off) = vh[it];
        }
        __syncthreads();
      }
      if (t + 1 < TT) {  // prefetch x_{t+1} (independent; overlaps h-GEMM + epilogue)
        if (l > 0) {
          const _Float16* sx = xsrc + (size_t)(t + 1) * HH;
#pragma unroll
          for (int it = 0; it < 8; ++it) {
            int q = tid + it * 256, row = q >> 6, c16 = q & 63;
            vx[it] = *(const u32x4*)((const char*)(sx + (size_t)row * TT * HH) + c16 * 16);
          }
        } else if (tid < 64) {
          int row = tid >> 1, half = tid & 1;
          vx0 = *(const u32x4*)(g_xbf + ((size_t)(32 * g + row) * TT + (t + 1)) * II + half * 8);
        }
      }
      if (t > 0) {
#pragma unroll
        for (int kt = 0; kt < 16; ++kt) {
          acc0 = MFMA16(ldsA(hs, 0, kt, lane), whhf[kt], acc0);
          acc1 = MFMA16(ldsA(hs, 1, kt, lane), whhf[kt], acc1);
        }
      }

      // ---- publish gate tiles ----
#pragma unroll
      for (int r = 0; r < 4; ++r) {
        gbuf[w][(kg * 4 + r) * 17 + col] = acc0[r];
        gbuf[w][(16 + kg * 4 + r) * 17 + col] = acc1[r];
      }
      __syncthreads();

      // ---- elementwise LSTM cell (c kept in fp32 regs), store h slice ----
      {
        int i0 = eb * 17 + ej;
        float i_0 = fsig(gbuf[0][i0]),  i_1 = fsig(gbuf[0][i0 + 1]);
        float f_0 = fsig(gbuf[1][i0]),  f_1 = fsig(gbuf[1][i0 + 1]);
        float t_0 = ftanh(gbuf[2][i0]), t_1 = ftanh(gbuf[2][i0 + 1]);
        float o_0 = fsig(gbuf[3][i0]),  o_1 = fsig(gbuf[3][i0 + 1]);
        c0 = f_0 * c0 + i_0 * t_0;
        c1 = f_1 * c1 + i_1 * t_1;
        float h0 = o_0 * ftanh(c0), h1 = o_1 * ftanh(c1);
        _Float16 hh0 = (_Float16)h0, hh1 = (_Float16)h1;
        unsigned pv = ((unsigned)__builtin_bit_cast(unsigned short, hh1) << 16) |
                      (unsigned)__builtin_bit_cast(unsigned short, hh0);
        _Float16* dst = hdst + ((size_t)eb * TT + t) * HH + jc * 16 + ej;
        st_cv(dst, pv);
      }

      // ---- drain stores (and prefetch), signal step completion ----
      asm volatile("s_waitcnt vmcnt(0)" ::: "memory");
      __syncthreads();
      if (tid == 0) {
        __hip_atomic_fetch_add(cown, 1u, __ATOMIC_RELAXED, __HIP_MEMORY_SCOPE_AGENT);
      }
    }
  }
}

// ---------------- FC head: out[b] = sigmoid(h_last[b] . fc_w + fc_b) ----------------
__global__ void fc_kernel(const float* __restrict__ fcw, const float* __restrict__ fcb,
                          float* __restrict__ out) {
  int b = blockIdx.x, lane = threadIdx.x;
  const _Float16* h = g_hbuf + ((size_t)3 * BB + b) * TT * HH + (size_t)(TT - 1) * HH + lane * 8;
  f16x8 hv = *(const f16x8*)h;
  const float* wp = fcw + lane * 8;
  float s = 0.f;
#pragma unroll
  for (int j = 0; j < 8; ++j) s += (float)hv[j] * wp[j];
#pragma unroll
  for (int off = 32; off; off >>= 1) s += __shfl_down(s, off, 64);
  if (lane == 0) out[b] = 1.f / (1.f + __expf(-(s + fcb[0])));
}

// ---------------- launch ----------------
extern "C" void kernel_launch(void* const* d_in, const int* in_sizes, int n_in,
                              void* d_out, int out_size, void* d_ws, size_t ws_size,
                              hipStream_t stream) {
  const float* x    = (const float*)d_in[0];
  const float* wih0 = (const float*)d_in[1];
  const float* whh0 = (const float*)d_in[2];
  const float* bih0 = (const float*)d_in[3];
  const float* bhh0 = (const float*)d_in[4];
  const float* wihr = (const float*)d_in[5];
  const float* whhr = (const float*)d_in[6];
  const float* bihr = (const float*)d_in[7];
  const float* bhhr = (const float*)d_in[8];
  const float* fcw  = (const float*)d_in[9];
  const float* fcb  = (const float*)d_in[10];

  prep_kernel<<<dim3(1024), dim3(256), 0, stream>>>(x, wih0, whh0, bih0, bhh0,
                                                    wihr, whhr, bihr, bhhr);
  lstm_kernel<<<dim3(256), dim3(256), 0, stream>>>();
  fc_kernel<<<dim3(256), dim3(64), 0, stream>>>(fcw, fcb, (float*)d_out);
}